// Round 12
// baseline (886.224 us; speedup 1.0000x reference)
//
#include <hip/hip_runtime.h>
#include <stdint.h>
#include <math.h>

// ---------------------------------------------------------------------------
// MultiScaleResidualQuantizer3D  (B=128, C=32, HW=16, N_E=4096, 10 scales)
// Round 12: round-9 base (best, 695us) + upconv de-stall.
//   - k_merge (PN>=8): coalesced SEG-winner fold -> compact idxf[int]; upconv
//     merge becomes 4B coalesced reads (was 8x-redundant scattered u64).
//     PN16 histogram folded into k_merge.
//   - upconv conv core: hv preloaded to regs in 8-ic chunks (batched ds_read,
//     single wait) so weight s_loads don't share lgkmcnt drains with DS.
//   - quant: SEG=16 uniform, mt=8, plain per-(seg,token) stores (round 9).
//   - scoring: MFMA fp16 3-term split (xh*ch + xl*ch + xh*cl), fp32 acc
//   - PHI_IDX = [0,0,0,1,1,2,2,2,3,3] (exact np.linspace tie resolution)
// ---------------------------------------------------------------------------

#define DEVI __device__ __forceinline__

static constexpr int NE = 4096;

typedef _Float16 half8 __attribute__((ext_vector_type(8)));
typedef float floatx4 __attribute__((ext_vector_type(4)));

DEVI unsigned fkey(float f) {
    unsigned u = __float_as_uint(f);
    return (u & 0x80000000u) ? ~u : (u | 0x80000000u);  // order-preserving
}
DEVI unsigned long long packSI(float s, unsigned idx) {
    // high: monotone score key; low: ~idx so ties prefer SMALLER idx (first max)
    return ((unsigned long long)fkey(s) << 32) | (unsigned)(~idx);
}
DEVI int unpackI(unsigned long long v) {
    return (int)(~(unsigned)(v & 0xFFFFFFFFull));
}
DEVI unsigned long long shflx(unsigned long long v, int m) {
    unsigned lo = (unsigned)v, hi = (unsigned)(v >> 32);
    lo = __shfl_xor(lo, m, 64);
    hi = __shfl_xor(hi, m, 64);
    return ((unsigned long long)hi << 32) | lo;
}
// value of left lane (x-1) within 16-lane row; x==0 -> 0  (row_shr:1)
DEVI float dppL(float v) {
    return __int_as_float(
        __builtin_amdgcn_update_dpp(0, __float_as_int(v), 0x111, 0xF, 0xF, true));
}
// value of right lane (x+1); x==15 -> 0  (row_shl:1)
DEVI float dppR(float v) {
    return __int_as_float(
        __builtin_amdgcn_update_dpp(0, __float_as_int(v), 0x101, 0xF, 0xF, true));
}

// --------------------------- setup kernel ----------------------------------
// blocks 0..15: codebook normalize + fp16 hi/lo split
// blocks 16..159: weight repack  wT[k][q8][ic][k9][o2], oc=(q8>>2)*16+(q8&3)*4+o2
// block 160: bicubic U matrices (f64 math) + zero lossAcc/hist
// blocks 161..1184: zero fhat
__global__ void __launch_bounds__(256) k_setup(const float* __restrict__ cb,
                                               const float* __restrict__ pw,
                                               _Float16* __restrict__ cbh,
                                               _Float16* __restrict__ cbl,
                                               float* __restrict__ wT,
                                               float* __restrict__ um,
                                               float* __restrict__ fhat,
                                               float* __restrict__ lossAcc) {
    int blk = blockIdx.x, tid = threadIdx.x;
    if (blk < 16) {
        int r = blk * 256 + tid;
        const float* src = cb + r * 32;
        float v[32];
        float ss = 0.f;
#pragma unroll
        for (int j = 0; j < 32; ++j) { v[j] = src[j]; ss += v[j] * v[j]; }
        float n = fmaxf(sqrtf(ss), 1e-12f);
#pragma unroll
        for (int j = 0; j < 32; ++j) {
            float x = v[j] / n;
            _Float16 h = (_Float16)x;
            cbh[r * 32 + j] = h;
            cbl[r * 32 + j] = (_Float16)(x - (float)h);
        }
    } else if (blk < 160) {
        int e = (blk - 16) * 256 + tid;             // < 36864
        int k = e / 9216, rem = e % 9216;
        int q8 = rem / 1152, rem2 = rem % 1152;
        int ic = rem2 / 36, r3 = rem2 % 36;
        int k9 = r3 / 4, o2 = r3 % 4;
        int oc = (q8 >> 2) * 16 + (q8 & 3) * 4 + o2;
        int ky = k9 / 3, kx = k9 % 3;
        wT[e] = pw[(((k * 32 + oc) * 32 + ic) * 3 + ky) * 3 + kx];
    } else if (blk == 160) {
        if (tid < 144) {
            const int pns[9] = {1, 2, 3, 4, 5, 6, 8, 10, 13};
            int si = tid / 16, y = tid % 16, pn = pns[si];
            double scale = (double)pn / 16.0;
            double src = ((double)y + 0.5) * scale - 0.5;
            double fl = floor(src);
            int i0 = (int)fl;
            double f = src - fl;
            float row[13];
            for (int j = 0; j < pn; ++j) row[j] = 0.f;
            const double a = -0.75;
#pragma unroll
            for (int off = -1; off <= 2; ++off) {
                double t2 = fabs(f - (double)off);
                double wgt;
                if (t2 <= 1.0)      wgt = ((a + 2.0) * t2 - (a + 3.0)) * t2 * t2 + 1.0;
                else if (t2 < 2.0)  wgt = (((t2 - 5.0) * t2 + 8.0) * t2 - 4.0) * a;
                else                wgt = 0.0;
                int j = i0 + off;
                j = j < 0 ? 0 : (j > pn - 1 ? pn - 1 : j);
                row[j] = (float)((double)row[j] + wgt);   // numpy f32 += f64
            }
            for (int j = 0; j < pn; ++j) um[si * 256 + y * pn + j] = row[j];
        } else {
            // zero lossAcc (16 f) + hist (4096 i32), contiguous
            for (int i = tid - 144; i < 4112; i += 112) ((int*)lossAcc)[i] = 0;
        }
    } else {
        int i = (blk - 161) * 1024 + tid * 4;
        float4 z = {0.f, 0.f, 0.f, 0.f};
        *(float4*)(fhat + i) = z;
    }
}

// ----------------------- per-scale kernels ---------------------------------

// area downsample of (f_input - f_hat) -> token-major fp16 hi/lo [t*32+c];
// pads tokens T..Tp with zeros
template <int PN>
__global__ void __launch_bounds__(256) k_down(const float* __restrict__ fin,
                                              const float* __restrict__ fhat,
                                              _Float16* __restrict__ xh,
                                              _Float16* __restrict__ xl) {
    constexpr int T = 128 * PN * PN;
    constexpr int Tp = ((T + 511) / 512) * 512;
    int id = blockIdx.x * 256 + threadIdx.x;
    if (id >= 32 * Tp) return;
    int t = id >> 5, c = id & 31;
    if (t >= T) { xh[id] = (_Float16)0.f; xl[id] = (_Float16)0.f; return; }
    int b = t / (PN * PN), r = t % (PN * PN), oy = r / PN, ox = r % PN;
    int sy = oy * 16 / PN, ey = ((oy + 1) * 16 + PN - 1) / PN;
    int sx = ox * 16 / PN, ex = ((ox + 1) * 16 + PN - 1) / PN;
    float wy = 1.f / (float)(ey - sy);
    float wx = 1.f / (float)(ex - sx);
    const float* pi = fin + b * 8192 + c * 256;
    const float* ph = fhat + b * 8192 + c * 256;
    float s = 0.f;
    for (int y = sy; y < ey; ++y)
        for (int x = sx; x < ex; ++x)
            s += pi[y * 16 + x] - ph[y * 16 + x];
    float v = s * (wy * wx);
    _Float16 h = (_Float16)v;
    xh[id] = h;
    xl[id] = (_Float16)(v - (float)h);
}

// MFMA cosine argmax. Block = 4 waves; wave = 128 tokens (8 M-tiles).
// Codes split into SEG segments across blocks; chunk of CH codes in LDS.
// Per-(seg,token) winner -> PLAIN coalesced store to bestp[seg*Tp + token].
template <int PN, int SEG>
__global__ void __launch_bounds__(256, 2) k_quant(
        const half8* __restrict__ xh, const half8* __restrict__ xl,
        const float4* __restrict__ cbh4, const float4* __restrict__ cbl4,
        unsigned long long* __restrict__ bestp) {
    constexpr int T = 128 * PN * PN;
    constexpr int Tp = ((T + 511) / 512) * 512;
    constexpr int TB = Tp / 512;
    constexpr int CPS = 4096 / SEG;                 // codes per segment
    constexpr int CH = (CPS < 128) ? CPS : 128;     // codes staged per chunk
    __shared__ __align__(16) _Float16 sh[CH * 40];  // stride 40 halfs (80B)
    __shared__ __align__(16) _Float16 sl[CH * 40];

    int tid = threadIdx.x;
    int bt = blockIdx.x % TB, seg = blockIdx.x / TB;
    int wv = tid >> 6, lane = tid & 63;
    int n0 = lane & 15, g = lane >> 4;
    int tokbase = bt * 512 + wv * 128;

    half8 ah[8], al[8];
#pragma unroll
    for (int mt = 0; mt < 8; ++mt) {
        int tok = tokbase + mt * 16 + n0;
        ah[mt] = xh[tok * 4 + g];
        al[mt] = xl[tok * 4 + g];
    }

    float mx[8][4];
    unsigned ib[8][4];
#pragma unroll
    for (int mt = 0; mt < 8; ++mt)
#pragma unroll
        for (int r = 0; r < 4; ++r) { mx[mt][r] = -3.0e38f; ib[mt][r] = 0u; }

    const floatx4 z4 = {0.f, 0.f, 0.f, 0.f};
    int cbase = seg * CPS;
    for (int cc0 = 0; cc0 < CPS; cc0 += CH) {
        __syncthreads();
        for (int e = tid; e < CH * 4; e += 256) {   // stage chunk (hi+lo)
            int code = e >> 2, q = e & 3;
            *(float4*)(sh + code * 40 + q * 8) = cbh4[(cbase + cc0 + code) * 4 + q];
            *(float4*)(sl + code * 40 + q * 8) = cbl4[(cbase + cc0 + code) * 4 + q];
        }
        __syncthreads();
#pragma unroll 2
        for (int nt = 0; nt < CH / 16; ++nt) {
            half8 bh = *(const half8*)(sh + (nt * 16 + n0) * 40 + g * 8);
            half8 bl = *(const half8*)(sl + (nt * 16 + n0) * 40 + g * 8);
            unsigned colb = (unsigned)(cbase + cc0 + nt * 16);
#pragma unroll
            for (int mt = 0; mt < 8; ++mt) {
                floatx4 c;
                c = __builtin_amdgcn_mfma_f32_16x16x32_f16(ah[mt], bh, z4, 0, 0, 0);
                c = __builtin_amdgcn_mfma_f32_16x16x32_f16(al[mt], bh, c,  0, 0, 0);
                c = __builtin_amdgcn_mfma_f32_16x16x32_f16(ah[mt], bl, c,  0, 0, 0);
#pragma unroll
                for (int r = 0; r < 4; ++r) {
                    bool gt = c[r] > mx[mt][r];
                    mx[mt][r] = gt ? c[r] : mx[mt][r];
                    ib[mt][r] = gt ? colb : ib[mt][r];
                }
            }
        }
    }

    unsigned long long* dst = bestp + (size_t)seg * Tp;
#pragma unroll
    for (int mt = 0; mt < 8; ++mt) {
#pragma unroll
        for (int r = 0; r < 4; ++r) {
            unsigned long long k = packSI(mx[mt][r], ib[mt][r] + (unsigned)n0);
            unsigned long long o;
            o = shflx(k, 1); k = (o > k) ? o : k;
            o = shflx(k, 2); k = (o > k) ? o : k;
            o = shflx(k, 4); k = (o > k) ? o : k;
            o = shflx(k, 8); k = (o > k) ? o : k;
            if (n0 == 0)
                dst[tokbase + mt * 16 + g * 4 + r] = k;   // unique slot, no atomic
        }
    }
}

// coalesced SEG-winner fold -> idxf[tok] (int). HIST: also histogram (PN16).
template <int PN, int SEG, bool HIST>
__global__ void __launch_bounds__(256) k_merge(
        const unsigned long long* __restrict__ bestp,
        int* __restrict__ idxf, int* __restrict__ hist) {
    constexpr int T = 128 * PN * PN;
    constexpr int Tp = ((T + 511) / 512) * 512;
    int t = blockIdx.x * 256 + threadIdx.x;
    if (t >= T) return;
    unsigned long long k = bestp[t];
#pragma unroll
    for (int s = 1; s < SEG; ++s) {
        unsigned long long o = bestp[(size_t)s * Tp + t];
        k = (o > k) ? o : k;
    }
    int idx = unpackI(k);
    idxf[t] = idx;
    if (HIST) atomicAdd(hist + idx, 1);
}

// idx read (merged: compact idxf; else SEG-merge) + gather + bicubic (6 rows)
// + 3x3 conv (phi) + fhat + loss.  grid 1024 = (img, quarter, oc-half);
// 256 thr = 4 waves x 64 px.  Conv core: hv preloaded per 8-ic chunk (DS and
// SMEM waits separated), DPP x-neighbors, 4 oc/thread.
template <int PN, int SEG, int K, bool LAST, bool MERGED>
__global__ void __launch_bounds__(256) k_upconv(
        const float* __restrict__ fin, float* __restrict__ fhat,
        const float* __restrict__ cbook,
        const unsigned long long* __restrict__ bestp,
        const int* __restrict__ idxf,
        const float* __restrict__ wT, const float* __restrict__ phib,
        const float* __restrict__ um, float* __restrict__ lossAcc,
        float* __restrict__ dout) {
    constexpr int NT = PN * PN;
    constexpr int T = 128 * NT;
    constexpr int Tp = ((T + 511) / 512) * 512;
    constexpr int RA = (PN < 16 && NT * 32 > 4096) ? NT * 32 : 4096;
    __shared__ __align__(16) float regionA[RA];          // h0, then S_hu (4096)
    __shared__ float hu1[(PN < 16) ? 32 * 6 * PN : 1];   // [c][rr][i]
    __shared__ float Us[(PN < 16) ? 16 * PN : 1];
    __shared__ int idxs[NT];
    __shared__ float red[4];
    float* S_hu = regionA;
    float* h0 = regionA;

    int img = blockIdx.x >> 3, q = (blockIdx.x >> 1) & 3, och = blockIdx.x & 1;
    int y0 = q * 4;
    int tid = threadIdx.x;

    if (MERGED) {
        for (int e = tid; e < NT; e += 256) idxs[e] = idxf[img * NT + e];
    } else {
        for (int e = tid; e < NT; e += 256) {
            int tok = img * NT + e;
            unsigned long long k = bestp[tok];
#pragma unroll
            for (int s = 1; s < SEG; ++s) {
                unsigned long long o = bestp[(size_t)s * Tp + tok];
                k = (o > k) ? o : k;
            }
            idxs[e] = unpackI(k);
        }
    }
    if (PN < 16)
        for (int e = tid; e < 16 * PN; e += 256) Us[e] = um[e];
    __syncthreads();

    if (PN == 16) {
        // direct gather into S_hu rows rr+1 (gy = y0-1+rr), zero out-of-image
        for (int e = tid; e < 3072; e += 256) {
            int c = e / 96, r = e % 96;
            int rr = r >> 4, x = r & 15;
            int gy = y0 - 1 + rr;
            float v = 0.f;
            if (gy >= 0 && gy <= 15) v = cbook[idxs[gy * 16 + x] * 32 + c];
            S_hu[c * 128 + (rr + 1) * 16 + x] = v;
        }
    } else {
        for (int e = tid; e < NT * 32; e += 256) {       // h0[tok][c]
            int tk = e >> 5, c = e & 31;
            h0[e] = cbook[idxs[tk] * 32 + c];
        }
        __syncthreads();
        // y-pass (6 needed rows): hu1[c][rr][i] = sum_j U[gy][j]*h0[j*PN+i][c]
        for (int e = tid; e < 6 * PN * 32; e += 256) {
            int c = e & 31, rest = e >> 5;
            int rr = rest / PN, i = rest % PN;
            int gy = y0 - 1 + rr;
            float s = 0.f;
            if (gy >= 0 && gy <= 15)
                for (int j = 0; j < PN; ++j)
                    s += Us[gy * PN + j] * h0[(j * PN + i) * 32 + c];
            hu1[(c * 6 + rr) * PN + i] = s;
        }
        __syncthreads();
        // x-pass -> S_hu (overwrites h0 region; h0 dead)
        for (int e = tid; e < 3072; e += 256) {
            int c = e / 96, r = e % 96;
            int rr = r >> 4, x = r & 15;
            int gy = y0 - 1 + rr;
            float s = 0.f;
            if (gy >= 0 && gy <= 15)
                for (int i = 0; i < PN; ++i)
                    s += Us[x * PN + i] * hu1[(c * 6 + rr) * PN + i];
            S_hu[c * 128 + (rr + 1) * 16 + x] = s;
        }
    }
    __syncthreads();

    // ---- conv core: 8-ic chunks, hv regs first (DS), then weights (SMEM) ----
    int px = tid & 63;
    int ocg = __builtin_amdgcn_readfirstlane(tid >> 6);  // wave id, uniform
    int yo = px >> 4, x = px & 15;
    int y = y0 + yo;
    int ry = yo + 2;                                     // center row in S_hu
    float acc[4] = {0.f, 0.f, 0.f, 0.f};
    const float* wk = wT + K * 9216 + (och * 4 + ocg) * 1152;  // [ic][k9][4]
#pragma unroll
    for (int icb = 0; icb < 32; icb += 8) {
        float hm[8], hc[8], hp[8];
#pragma unroll
        for (int i = 0; i < 8; ++i) {                    // batched ds_reads
            int a = (icb + i) * 128 + ry * 16 + x;
            hm[i] = S_hu[a - 16];
            hc[i] = S_hu[a];
            hp[i] = S_hu[a + 16];
        }
#pragma unroll
        for (int i = 0; i < 8; ++i) {                    // SMEM+VALU only
            float cm = hm[i], cc = hc[i], cp = hp[i];
            float lm = dppL(cm), lc = dppL(cc), lp = dppL(cp);
            float rm = dppR(cm), rc = dppR(cc), rp = dppR(cp);
            const float* w = wk + (icb + i) * 36;
#pragma unroll
            for (int o = 0; o < 4; ++o) {
                float s = acc[o];
                s = fmaf(w[o],      lm, s);   // ky=0 (row y-1): x-1, x, x+1
                s = fmaf(w[4 + o],  cm, s);
                s = fmaf(w[8 + o],  rm, s);
                s = fmaf(w[12 + o], lc, s);   // ky=1
                s = fmaf(w[16 + o], cc, s);
                s = fmaf(w[20 + o], rc, s);
                s = fmaf(w[24 + o], lp, s);   // ky=2
                s = fmaf(w[28 + o], cp, s);
                s = fmaf(w[32 + o], rp, s);
                acc[o] = s;
            }
        }
    }

    // epilogue: 4 oc per thread at its pixel
    float ss = 0.f;
    {
        int oc0 = och * 16 + ocg * 4;
        int gbase = img * 8192 + oc0 * 256 + y * 16 + x;
        const float* bias = phib + K * 32 + oc0;
#pragma unroll
        for (int oi = 0; oi < 4; ++oi) {
            float conv = acc[oi] + bias[oi];
            float hval = 0.5f * S_hu[(oc0 + oi) * 128 + ry * 16 + x] + 0.5f * conv;
            float fh = fhat[gbase + oi * 256] + hval;
            fhat[gbase + oi * 256] = fh;
            if (LAST) dout[gbase + oi * 256] = fh;
            float d = fh - fin[gbase + oi * 256];
            ss = fmaf(d, d, ss);
        }
    }
    int lane = tid & 63;
#pragma unroll
    for (int m = 1; m < 64; m <<= 1) ss += __shfl_xor(ss, m, 64);
    if (lane == 0) red[tid >> 6] = ss;
    __syncthreads();
    if (tid == 0) atomicAdd(lossAcc, red[0] + red[1] + red[2] + red[3]);
}

__global__ void __launch_bounds__(256) k_final(const float* __restrict__ lossAcc,
                                               const int* __restrict__ hist,
                                               float* __restrict__ out) {
    __shared__ float red[256];
    int tid = threadIdx.x;
    float s = 0.f;
    for (int i = tid; i < 4096; i += 256) {
        float p = (float)hist[i] * (1.f / 32768.f);
        s += p * logf(p + 1e-10f);
    }
    red[tid] = s;
    __syncthreads();
    for (int k = 128; k > 0; k >>= 1) {
        if (tid < k) red[tid] += red[tid + k];
        __syncthreads();
    }
    if (tid == 0) {
        out[1048577] = expf(-red[0]);
        float L = 0.f;
        for (int si = 0; si < 10; ++si) L += lossAcc[si];
        out[1048576] = L * 1.25f / 1048576.f * 0.1f;
    }
}

// ------------------------------ launch -------------------------------------

extern "C" void kernel_launch(void* const* d_in, const int* in_sizes, int n_in,
                              void* d_out, int out_size, void* d_ws, size_t ws_size,
                              hipStream_t stream) {
    const float* f_in  = (const float*)d_in[0];   // [128,32,16,16]
    const float* cbook = (const float*)d_in[1];   // [4096,32]
    const float* phiw  = (const float*)d_in[2];   // [4,32,32,3,3]
    const float* phib  = (const float*)d_in[3];   // [4,32]
    float* out = (float*)d_out;
    char* base = (char*)d_ws;

    float* fhat    = (float*)(base);                       // 4,194,304 B
    float* lossAcc = (float*)(base + 4194304);             // 64 B
    int*   hist    = (int*)  (base + 4194368);             // 16,384 B
    float* wT      = (float*)(base + 4210752);             // 147,456 B
    float* um      = (float*)(base + 4358208);             // 9,216 B
    _Float16* cbh  = (_Float16*)(base + 4367424);          // 262,144 B
    _Float16* cbl  = (_Float16*)(base + 4629568);          // 262,144 B
    _Float16* xh   = (_Float16*)(base + 4891712);          // 2,097,152 B
    _Float16* xl   = (_Float16*)(base + 6988864);          // 2,097,152 B
    unsigned long long* bestp = (unsigned long long*)(base + 9086016);  // 4,194,304 B
    int* idxf      = (int*)(base + 13280320);              // 131,072 B

    k_setup<<<1185, 256, 0, stream>>>(cbook, phiw, cbh, cbl, wT, um, fhat, lossAcc);

#define SCALE(SI, PN, K, LAST)                                                         \
    {                                                                                  \
        constexpr int T = 128 * PN * PN;                                               \
        constexpr int Tp = ((T + 511) / 512) * 512;                                    \
        constexpr int TB = Tp / 512;                                                   \
        k_down<PN><<<(Tp * 32) / 256, 256, 0, stream>>>(f_in, fhat, xh, xl);           \
        k_quant<PN, 16><<<TB * 16, 256, 0, stream>>>(                                  \
            (const half8*)xh, (const half8*)xl, (const float4*)cbh,                    \
            (const float4*)cbl, bestp);                                                \
        k_upconv<PN, 16, K, LAST, false><<<1024, 256, 0, stream>>>(                    \
            f_in, fhat, cbook, bestp, idxf, wT, phib, um + SI * 256, lossAcc + SI,     \
            out);                                                                      \
    }
#define SCALE_M(SI, PN, K, LAST, HIST)                                                 \
    {                                                                                  \
        constexpr int T = 128 * PN * PN;                                               \
        constexpr int Tp = ((T + 511) / 512) * 512;                                    \
        constexpr int TB = Tp / 512;                                                   \
        k_down<PN><<<(Tp * 32) / 256, 256, 0, stream>>>(f_in, fhat, xh, xl);           \
        k_quant<PN, 16><<<TB * 16, 256, 0, stream>>>(                                  \
            (const half8*)xh, (const half8*)xl, (const float4*)cbh,                    \
            (const float4*)cbl, bestp);                                                \
        k_merge<PN, 16, HIST><<<Tp / 256, 256, 0, stream>>>(bestp, idxf, hist);        \
        k_upconv<PN, 16, K, LAST, true><<<1024, 256, 0, stream>>>(                     \
            f_in, fhat, cbook, bestp, idxf, wT, phib, um + SI * 256, lossAcc + SI,     \
            out);                                                                      \
    }
    SCALE(0, 1, 0, false);
    SCALE(1, 2, 0, false);
    SCALE(2, 3, 0, false);
    SCALE(3, 4, 1, false);
    SCALE(4, 5, 1, false);
    SCALE(5, 6, 2, false);
    SCALE_M(6, 8, 2, false, false);
    SCALE_M(7, 10, 2, false, false);
    SCALE_M(8, 13, 3, false, false);
    SCALE_M(9, 16, 3, true, true);
#undef SCALE
#undef SCALE_M
    k_final<<<1, 256, 0, stream>>>(lossAcc, hist, out);
}

// Round 13
// 693.898 us; speedup vs baseline: 1.2772x; 1.2772x over previous
//
#include <hip/hip_runtime.h>
#include <stdint.h>
#include <math.h>

// ---------------------------------------------------------------------------
// MultiScaleResidualQuantizer3D  (B=128, C=32, HW=16, N_E=4096, 10 scales)
// Round 13 == Round 9 verbatim (best measured: 695us). Reproducibility probe:
//   rounds 10-12 showed +-20-40% session noise on byte-identical kernels
//   (k_quant<16,16> 44.8 vs 63.5us, identical counters). This is the stable
//   optimum of the decomposition:
//   k_down (coalesced residual+downsample -> fp16 hi/lo xh/xl)
//   -> k_quant (MFMA 3-term fp16 split, SEG=16, plain per-(seg,token) stores)
//   -> k_upconv (SEG-merge + gather + bicubic 6 rows + DPP conv + fhat + loss)
//   - PHI_IDX = [0,0,0,1,1,2,2,2,3,3] (exact np.linspace tie resolution)
// ---------------------------------------------------------------------------

#define DEVI __device__ __forceinline__

static constexpr int NE = 4096;

typedef _Float16 half8 __attribute__((ext_vector_type(8)));
typedef float floatx4 __attribute__((ext_vector_type(4)));

DEVI unsigned fkey(float f) {
    unsigned u = __float_as_uint(f);
    return (u & 0x80000000u) ? ~u : (u | 0x80000000u);  // order-preserving
}
DEVI unsigned long long packSI(float s, unsigned idx) {
    // high: monotone score key; low: ~idx so ties prefer SMALLER idx (first max)
    return ((unsigned long long)fkey(s) << 32) | (unsigned)(~idx);
}
DEVI int unpackI(unsigned long long v) {
    return (int)(~(unsigned)(v & 0xFFFFFFFFull));
}
DEVI unsigned long long shflx(unsigned long long v, int m) {
    unsigned lo = (unsigned)v, hi = (unsigned)(v >> 32);
    lo = __shfl_xor(lo, m, 64);
    hi = __shfl_xor(hi, m, 64);
    return ((unsigned long long)hi << 32) | lo;
}
// value of left lane (x-1) within 16-lane row; x==0 -> 0  (row_shr:1)
DEVI float dppL(float v) {
    return __int_as_float(
        __builtin_amdgcn_update_dpp(0, __float_as_int(v), 0x111, 0xF, 0xF, true));
}
// value of right lane (x+1); x==15 -> 0  (row_shl:1)
DEVI float dppR(float v) {
    return __int_as_float(
        __builtin_amdgcn_update_dpp(0, __float_as_int(v), 0x101, 0xF, 0xF, true));
}

// --------------------------- setup kernel ----------------------------------
// blocks 0..15: codebook normalize + fp16 hi/lo split
// blocks 16..159: weight repack  wT[k][q8][ic][k9][o2], oc=(q8>>2)*16+(q8&3)*4+o2
// block 160: bicubic U matrices (f64 math) + zero lossAcc/hist
// blocks 161..1184: zero fhat
__global__ void __launch_bounds__(256) k_setup(const float* __restrict__ cb,
                                               const float* __restrict__ pw,
                                               _Float16* __restrict__ cbh,
                                               _Float16* __restrict__ cbl,
                                               float* __restrict__ wT,
                                               float* __restrict__ um,
                                               float* __restrict__ fhat,
                                               float* __restrict__ lossAcc) {
    int blk = blockIdx.x, tid = threadIdx.x;
    if (blk < 16) {
        int r = blk * 256 + tid;
        const float* src = cb + r * 32;
        float v[32];
        float ss = 0.f;
#pragma unroll
        for (int j = 0; j < 32; ++j) { v[j] = src[j]; ss += v[j] * v[j]; }
        float n = fmaxf(sqrtf(ss), 1e-12f);
#pragma unroll
        for (int j = 0; j < 32; ++j) {
            float x = v[j] / n;
            _Float16 h = (_Float16)x;
            cbh[r * 32 + j] = h;
            cbl[r * 32 + j] = (_Float16)(x - (float)h);
        }
    } else if (blk < 160) {
        int e = (blk - 16) * 256 + tid;             // < 36864
        int k = e / 9216, rem = e % 9216;
        int q8 = rem / 1152, rem2 = rem % 1152;
        int ic = rem2 / 36, r3 = rem2 % 36;
        int k9 = r3 / 4, o2 = r3 % 4;
        int oc = (q8 >> 2) * 16 + (q8 & 3) * 4 + o2;
        int ky = k9 / 3, kx = k9 % 3;
        wT[e] = pw[(((k * 32 + oc) * 32 + ic) * 3 + ky) * 3 + kx];
    } else if (blk == 160) {
        if (tid < 144) {
            const int pns[9] = {1, 2, 3, 4, 5, 6, 8, 10, 13};
            int si = tid / 16, y = tid % 16, pn = pns[si];
            double scale = (double)pn / 16.0;
            double src = ((double)y + 0.5) * scale - 0.5;
            double fl = floor(src);
            int i0 = (int)fl;
            double f = src - fl;
            float row[13];
            for (int j = 0; j < pn; ++j) row[j] = 0.f;
            const double a = -0.75;
#pragma unroll
            for (int off = -1; off <= 2; ++off) {
                double t2 = fabs(f - (double)off);
                double wgt;
                if (t2 <= 1.0)      wgt = ((a + 2.0) * t2 - (a + 3.0)) * t2 * t2 + 1.0;
                else if (t2 < 2.0)  wgt = (((t2 - 5.0) * t2 + 8.0) * t2 - 4.0) * a;
                else                wgt = 0.0;
                int j = i0 + off;
                j = j < 0 ? 0 : (j > pn - 1 ? pn - 1 : j);
                row[j] = (float)((double)row[j] + wgt);   // numpy f32 += f64
            }
            for (int j = 0; j < pn; ++j) um[si * 256 + y * pn + j] = row[j];
        } else {
            // zero lossAcc (16 f) + hist (4096 i32), contiguous
            for (int i = tid - 144; i < 4112; i += 112) ((int*)lossAcc)[i] = 0;
        }
    } else {
        int i = (blk - 161) * 1024 + tid * 4;
        float4 z = {0.f, 0.f, 0.f, 0.f};
        *(float4*)(fhat + i) = z;
    }
}

// ----------------------- per-scale kernels ---------------------------------

// area downsample of (f_input - f_hat) -> token-major fp16 hi/lo [t*32+c];
// pads tokens T..Tp with zeros
template <int PN>
__global__ void __launch_bounds__(256) k_down(const float* __restrict__ fin,
                                              const float* __restrict__ fhat,
                                              _Float16* __restrict__ xh,
                                              _Float16* __restrict__ xl) {
    constexpr int T = 128 * PN * PN;
    constexpr int Tp = ((T + 511) / 512) * 512;
    int id = blockIdx.x * 256 + threadIdx.x;
    if (id >= 32 * Tp) return;
    int t = id >> 5, c = id & 31;
    if (t >= T) { xh[id] = (_Float16)0.f; xl[id] = (_Float16)0.f; return; }
    int b = t / (PN * PN), r = t % (PN * PN), oy = r / PN, ox = r % PN;
    int sy = oy * 16 / PN, ey = ((oy + 1) * 16 + PN - 1) / PN;
    int sx = ox * 16 / PN, ex = ((ox + 1) * 16 + PN - 1) / PN;
    float wy = 1.f / (float)(ey - sy);
    float wx = 1.f / (float)(ex - sx);
    const float* pi = fin + b * 8192 + c * 256;
    const float* ph = fhat + b * 8192 + c * 256;
    float s = 0.f;
    for (int y = sy; y < ey; ++y)
        for (int x = sx; x < ex; ++x)
            s += pi[y * 16 + x] - ph[y * 16 + x];
    float v = s * (wy * wx);
    _Float16 h = (_Float16)v;
    xh[id] = h;
    xl[id] = (_Float16)(v - (float)h);
}

// MFMA cosine argmax. Block = 4 waves; wave = 128 tokens (8 M-tiles).
// Codes split into SEG segments across blocks; chunk of CH codes in LDS.
// Per-(seg,token) winner -> PLAIN coalesced store to bestp[seg*Tp + token].
template <int PN, int SEG>
__global__ void __launch_bounds__(256, 2) k_quant(
        const half8* __restrict__ xh, const half8* __restrict__ xl,
        const float4* __restrict__ cbh4, const float4* __restrict__ cbl4,
        unsigned long long* __restrict__ bestp) {
    constexpr int T = 128 * PN * PN;
    constexpr int Tp = ((T + 511) / 512) * 512;
    constexpr int TB = Tp / 512;
    constexpr int CPS = 4096 / SEG;                 // codes per segment
    constexpr int CH = (CPS < 128) ? CPS : 128;     // codes staged per chunk
    __shared__ __align__(16) _Float16 sh[CH * 40];  // stride 40 halfs (80B)
    __shared__ __align__(16) _Float16 sl[CH * 40];

    int tid = threadIdx.x;
    int bt = blockIdx.x % TB, seg = blockIdx.x / TB;
    int wv = tid >> 6, lane = tid & 63;
    int n0 = lane & 15, g = lane >> 4;
    int tokbase = bt * 512 + wv * 128;

    half8 ah[8], al[8];
#pragma unroll
    for (int mt = 0; mt < 8; ++mt) {
        int tok = tokbase + mt * 16 + n0;
        ah[mt] = xh[tok * 4 + g];
        al[mt] = xl[tok * 4 + g];
    }

    float mx[8][4];
    unsigned ib[8][4];
#pragma unroll
    for (int mt = 0; mt < 8; ++mt)
#pragma unroll
        for (int r = 0; r < 4; ++r) { mx[mt][r] = -3.0e38f; ib[mt][r] = 0u; }

    const floatx4 z4 = {0.f, 0.f, 0.f, 0.f};
    int cbase = seg * CPS;
    for (int cc0 = 0; cc0 < CPS; cc0 += CH) {
        __syncthreads();
        for (int e = tid; e < CH * 4; e += 256) {   // stage chunk (hi+lo)
            int code = e >> 2, q = e & 3;
            *(float4*)(sh + code * 40 + q * 8) = cbh4[(cbase + cc0 + code) * 4 + q];
            *(float4*)(sl + code * 40 + q * 8) = cbl4[(cbase + cc0 + code) * 4 + q];
        }
        __syncthreads();
#pragma unroll 2
        for (int nt = 0; nt < CH / 16; ++nt) {
            half8 bh = *(const half8*)(sh + (nt * 16 + n0) * 40 + g * 8);
            half8 bl = *(const half8*)(sl + (nt * 16 + n0) * 40 + g * 8);
            unsigned colb = (unsigned)(cbase + cc0 + nt * 16);
#pragma unroll
            for (int mt = 0; mt < 8; ++mt) {
                floatx4 c;
                c = __builtin_amdgcn_mfma_f32_16x16x32_f16(ah[mt], bh, z4, 0, 0, 0);
                c = __builtin_amdgcn_mfma_f32_16x16x32_f16(al[mt], bh, c,  0, 0, 0);
                c = __builtin_amdgcn_mfma_f32_16x16x32_f16(ah[mt], bl, c,  0, 0, 0);
#pragma unroll
                for (int r = 0; r < 4; ++r) {
                    bool gt = c[r] > mx[mt][r];
                    mx[mt][r] = gt ? c[r] : mx[mt][r];
                    ib[mt][r] = gt ? colb : ib[mt][r];
                }
            }
        }
    }

    unsigned long long* dst = bestp + (size_t)seg * Tp;
#pragma unroll
    for (int mt = 0; mt < 8; ++mt) {
#pragma unroll
        for (int r = 0; r < 4; ++r) {
            unsigned long long k = packSI(mx[mt][r], ib[mt][r] + (unsigned)n0);
            unsigned long long o;
            o = shflx(k, 1); k = (o > k) ? o : k;
            o = shflx(k, 2); k = (o > k) ? o : k;
            o = shflx(k, 4); k = (o > k) ? o : k;
            o = shflx(k, 8); k = (o > k) ? o : k;
            if (n0 == 0)
                dst[tokbase + mt * 16 + g * 4 + r] = k;   // unique slot, no atomic
        }
    }
}

// SEG-merge argmax + gather + bicubic (6 rows) + 3x3 conv (phi) + fhat + loss.
// grid 1024 = (img, quarter of 4 rows, oc-half); 256 thr = 4 waves x 64 px.
// S_hu overlays h0 (h0 dead after y-pass).  Conv core: DPP x-neighbors,
// repacked contiguous weights, 4 oc/thread.
template <int PN, int SEG, int K, bool LAST>
__global__ void __launch_bounds__(256) k_upconv(
        const float* __restrict__ fin, float* __restrict__ fhat,
        const float* __restrict__ cbook,
        const unsigned long long* __restrict__ bestp,
        const float* __restrict__ wT, const float* __restrict__ phib,
        const float* __restrict__ um, float* __restrict__ lossAcc,
        int* __restrict__ hist, float* __restrict__ dout) {
    constexpr int NT = PN * PN;
    constexpr int T = 128 * NT;
    constexpr int Tp = ((T + 511) / 512) * 512;
    constexpr int RA = (PN < 16 && NT * 32 > 4096) ? NT * 32 : 4096;
    __shared__ __align__(16) float regionA[RA];          // h0, then S_hu (4096)
    __shared__ float hu1[(PN < 16) ? 32 * 6 * PN : 1];   // [c][rr][i]
    __shared__ float Us[(PN < 16) ? 16 * PN : 1];
    __shared__ int idxs[NT];
    __shared__ float red[4];
    float* S_hu = regionA;
    float* h0 = regionA;

    int img = blockIdx.x >> 3, q = (blockIdx.x >> 1) & 3, och = blockIdx.x & 1;
    int y0 = q * 4;
    int tid = threadIdx.x;

    // SEG-way merge of per-segment winners (coalesced per segment pass)
    for (int e = tid; e < NT; e += 256) {
        int tok = img * NT + e;
        unsigned long long k = bestp[tok];
#pragma unroll
        for (int s = 1; s < SEG; ++s) {
            unsigned long long o = bestp[(size_t)s * Tp + tok];
            k = (o > k) ? o : k;
        }
        idxs[e] = unpackI(k);
    }
    if (PN < 16)
        for (int e = tid; e < 16 * PN; e += 256) Us[e] = um[e];
    __syncthreads();

    if (PN == 16) {
        if (LAST && och == 0 && tid < 64)    // this quarter's 64 tokens
            atomicAdd(hist + idxs[y0 * 16 + tid], 1);
        // direct gather into S_hu rows rr+1 (gy = y0-1+rr), zero out-of-image
        for (int e = tid; e < 3072; e += 256) {
            int c = e / 96, r = e % 96;
            int rr = r >> 4, x = r & 15;
            int gy = y0 - 1 + rr;
            float v = 0.f;
            if (gy >= 0 && gy <= 15) v = cbook[idxs[gy * 16 + x] * 32 + c];
            S_hu[c * 128 + (rr + 1) * 16 + x] = v;
        }
    } else {
        for (int e = tid; e < NT * 32; e += 256) {       // h0[tok][c]
            int tk = e >> 5, c = e & 31;
            h0[e] = cbook[idxs[tk] * 32 + c];
        }
        __syncthreads();
        // y-pass (6 needed rows): hu1[c][rr][i] = sum_j U[gy][j]*h0[j*PN+i][c]
        for (int e = tid; e < 6 * PN * 32; e += 256) {
            int c = e & 31, rest = e >> 5;
            int rr = rest / PN, i = rest % PN;
            int gy = y0 - 1 + rr;
            float s = 0.f;
            if (gy >= 0 && gy <= 15)
                for (int j = 0; j < PN; ++j)
                    s += Us[gy * PN + j] * h0[(j * PN + i) * 32 + c];
            hu1[(c * 6 + rr) * PN + i] = s;
        }
        __syncthreads();
        // x-pass -> S_hu (overwrites h0 region; h0 dead)
        for (int e = tid; e < 3072; e += 256) {
            int c = e / 96, r = e % 96;
            int rr = r >> 4, x = r & 15;
            int gy = y0 - 1 + rr;
            float s = 0.f;
            if (gy >= 0 && gy <= 15)
                for (int i = 0; i < PN; ++i)
                    s += Us[x * PN + i] * hu1[(c * 6 + rr) * PN + i];
            S_hu[c * 128 + (rr + 1) * 16 + x] = s;
        }
    }
    __syncthreads();

    // ---- conv core: DPP x-neighbors, 4 oc/thread ----
    int px = tid & 63;
    int ocg = __builtin_amdgcn_readfirstlane(tid >> 6);  // wave id, uniform
    int yo = px >> 4, x = px & 15;
    int y = y0 + yo;
    int ry = yo + 2;                                     // center row in S_hu
    float acc[4] = {0.f, 0.f, 0.f, 0.f};
    const float* wk = wT + K * 9216 + (och * 4 + ocg) * 1152;  // [ic][k9][4]
#pragma unroll 4
    for (int ic = 0; ic < 32; ++ic) {
        int a = ic * 128 + ry * 16 + x;
        float cm = S_hu[a - 16], cc = S_hu[a], cp = S_hu[a + 16];
        float lm = dppL(cm), lc = dppL(cc), lp = dppL(cp);
        float rm = dppR(cm), rc = dppR(cc), rp = dppR(cp);
        const float* w = wk + ic * 36;
#pragma unroll
        for (int o = 0; o < 4; ++o) {
            float s = acc[o];
            s = fmaf(w[o],      lm, s);   // ky=0 (row y-1): x-1, x, x+1
            s = fmaf(w[4 + o],  cm, s);
            s = fmaf(w[8 + o],  rm, s);
            s = fmaf(w[12 + o], lc, s);   // ky=1
            s = fmaf(w[16 + o], cc, s);
            s = fmaf(w[20 + o], rc, s);
            s = fmaf(w[24 + o], lp, s);   // ky=2
            s = fmaf(w[28 + o], cp, s);
            s = fmaf(w[32 + o], rp, s);
            acc[o] = s;
        }
    }

    // epilogue: 4 oc per thread at its pixel
    float ss = 0.f;
    {
        int oc0 = och * 16 + ocg * 4;
        int gbase = img * 8192 + oc0 * 256 + y * 16 + x;
        const float* bias = phib + K * 32 + oc0;
#pragma unroll
        for (int oi = 0; oi < 4; ++oi) {
            float conv = acc[oi] + bias[oi];
            float hval = 0.5f * S_hu[(oc0 + oi) * 128 + ry * 16 + x] + 0.5f * conv;
            float fh = fhat[gbase + oi * 256] + hval;
            fhat[gbase + oi * 256] = fh;
            if (LAST) dout[gbase + oi * 256] = fh;
            float d = fh - fin[gbase + oi * 256];
            ss = fmaf(d, d, ss);
        }
    }
    int lane = tid & 63;
#pragma unroll
    for (int m = 1; m < 64; m <<= 1) ss += __shfl_xor(ss, m, 64);
    if (lane == 0) red[tid >> 6] = ss;
    __syncthreads();
    if (tid == 0) atomicAdd(lossAcc, red[0] + red[1] + red[2] + red[3]);
}

__global__ void __launch_bounds__(256) k_final(const float* __restrict__ lossAcc,
                                               const int* __restrict__ hist,
                                               float* __restrict__ out) {
    __shared__ float red[256];
    int tid = threadIdx.x;
    float s = 0.f;
    for (int i = tid; i < 4096; i += 256) {
        float p = (float)hist[i] * (1.f / 32768.f);
        s += p * logf(p + 1e-10f);
    }
    red[tid] = s;
    __syncthreads();
    for (int k = 128; k > 0; k >>= 1) {
        if (tid < k) red[tid] += red[tid + k];
        __syncthreads();
    }
    if (tid == 0) {
        out[1048577] = expf(-red[0]);
        float L = 0.f;
        for (int si = 0; si < 10; ++si) L += lossAcc[si];
        out[1048576] = L * 1.25f / 1048576.f * 0.1f;
    }
}

// ------------------------------ launch -------------------------------------

extern "C" void kernel_launch(void* const* d_in, const int* in_sizes, int n_in,
                              void* d_out, int out_size, void* d_ws, size_t ws_size,
                              hipStream_t stream) {
    const float* f_in  = (const float*)d_in[0];   // [128,32,16,16]
    const float* cbook = (const float*)d_in[1];   // [4096,32]
    const float* phiw  = (const float*)d_in[2];   // [4,32,32,3,3]
    const float* phib  = (const float*)d_in[3];   // [4,32]
    float* out = (float*)d_out;
    char* base = (char*)d_ws;

    float* fhat    = (float*)(base);                       // 4,194,304 B
    float* lossAcc = (float*)(base + 4194304);             // 64 B
    int*   hist    = (int*)  (base + 4194368);             // 16,384 B
    float* wT      = (float*)(base + 4210752);             // 147,456 B
    float* um      = (float*)(base + 4358208);             // 9,216 B
    _Float16* cbh  = (_Float16*)(base + 4367424);          // 262,144 B
    _Float16* cbl  = (_Float16*)(base + 4629568);          // 262,144 B
    _Float16* xh   = (_Float16*)(base + 4891712);          // 2,097,152 B
    _Float16* xl   = (_Float16*)(base + 6988864);          // 2,097,152 B
    unsigned long long* bestp = (unsigned long long*)(base + 9086016);  // 4,194,304 B

    k_setup<<<1185, 256, 0, stream>>>(cbook, phiw, cbh, cbl, wT, um, fhat, lossAcc);

#define SCALE(SI, PN, K, LAST)                                                         \
    {                                                                                  \
        constexpr int T = 128 * PN * PN;                                               \
        constexpr int Tp = ((T + 511) / 512) * 512;                                    \
        constexpr int TB = Tp / 512;                                                   \
        k_down<PN><<<(Tp * 32) / 256, 256, 0, stream>>>(f_in, fhat, xh, xl);           \
        k_quant<PN, 16><<<TB * 16, 256, 0, stream>>>(                                  \
            (const half8*)xh, (const half8*)xl, (const float4*)cbh,                    \
            (const float4*)cbl, bestp);                                                \
        k_upconv<PN, 16, K, LAST><<<1024, 256, 0, stream>>>(                           \
            f_in, fhat, cbook, bestp, wT, phib, um + SI * 256, lossAcc + SI, hist,     \
            out);                                                                      \
    }
    SCALE(0, 1, 0, false);
    SCALE(1, 2, 0, false);
    SCALE(2, 3, 0, false);
    SCALE(3, 4, 1, false);
    SCALE(4, 5, 1, false);
    SCALE(5, 6, 2, false);
    SCALE(6, 8, 2, false);
    SCALE(7, 10, 2, false);
    SCALE(8, 13, 3, false);
    SCALE(9, 16, 3, true);
#undef SCALE
    k_final<<<1, 256, 0, stream>>>(lossAcc, hist, out);
}